// Round 17
// baseline (402.263 us; speedup 1.0000x reference)
//
#include <hip/hip_runtime.h>

// ---------------------------------------------------------------------------
// FastRCNN head: RoIPool + FC(25088->4096) + FC(4096->4096) + heads (21/84).
// R17: the wall was the per-CU LDS port — B-frags were 256 scalar ds_read_b32
// per CU-iter (~1500cy, m134 rate) vs 1600cy HBM budget. Fix: pair-packed
// bf16 Bu (R7-validated layout), reg-staged B (16 coalesced f32/thread,
// loads issued 1 iter early = T14), 2 ds_write_b128/thread; B-frag read
// becomes 1 ds_read_b128 per nf (8/wave) with NO cvt in the MFMA path.
// Per-CU LDS ~2000 -> ~860cy. A via gll16 (R16); Bu 4-buffer; vmcnt(24).
// ---------------------------------------------------------------------------

typedef __attribute__((ext_vector_type(8))) __bf16 bf16x8;
typedef __attribute__((ext_vector_type(4))) float f32x4;
typedef __attribute__((ext_vector_type(4))) unsigned int u32x4;

#define N_ROIS 512
#define FH 50
#define FW 50
#define KK1 25088      // 512*49
#define D1 4096
#define BK 32

__device__ __forceinline__ void gll16(const void* g, void* l) {
  __builtin_amdgcn_global_load_lds(
      (const __attribute__((address_space(1))) void*)g,
      (__attribute__((address_space(3))) void*)l, 16, 0, 0);
}

// ---------------------------------------------------------------------------
// RoIPool: block = (roi, channel-group of 64). 4096 blocks (validated R5-R16).
// ---------------------------------------------------------------------------
__global__ __launch_bounds__(256) void roipool_kernel(
    const float* __restrict__ x, const float* __restrict__ rois,
    __bf16* __restrict__ pooled) {
  const int bid = blockIdx.x;
  const int roi = bid >> 3;
  const int cg = bid & 7;
  const float s = 0.0625f;
  const float r0 = rois[roi * 4 + 0], r1 = rois[roi * 4 + 1];
  const float r2 = rois[roi * 4 + 2], r3 = rois[roi * 4 + 3];
  int x1 = (int)(r0 * s); x1 = min(max(x1, 0), FW - 1);
  int y1 = (int)(r1 * s); y1 = min(max(y1, 0), FH - 1);
  int x2 = (int)(r2 * s); x2 = min(max(x2, 0), FW - 1);
  int y2 = (int)(r3 * s); y2 = min(max(y2, 0), FH - 1);
  const int ww = x2 - x1 + 1, hh = y2 - y1 + 1;
  __shared__ int cs[7], ce[7], rs[7], re[7];
  if (threadIdx.x < 7) {
    int i = threadIdx.x;
    cs[i] = x1 + (i * ww) / 7;
    ce[i] = x1 + ((i + 1) * ww + 6) / 7;
    rs[i] = y1 + (i * hh) / 7;
    re[i] = y1 + ((i + 1) * hh + 6) / 7;
  }
  __syncthreads();
  for (int idx = threadIdx.x; idx < 64 * 49; idx += 256) {
    int cl = idx / 49;
    int p = idx - cl * 49;
    int py = p / 7, px = p - py * 7;
    const int c = cg * 64 + cl;
    const float* base = x + (size_t)c * (FH * FW);
    float m = -3.402823466e38f;
    for (int y = rs[py]; y < re[py]; ++y) {
      const float* rowp = base + y * FW;
      for (int xx = cs[px]; xx < ce[px]; ++xx) m = fmaxf(m, rowp[xx]);
    }
    pooled[(size_t)roi * KK1 + c * 49 + p] = (__bf16)m;
  }
}

// ---------------------------------------------------------------------------
// gemm_pipe: part[z][512][npad] = A[512,K](bf16) @ B[K,N](fp32, N%128==0)
// 256 thr = 4 waves; wave w owns rows w*128..+127 x all 128 cols.
// A: 8 gll16/wave/iter -> A_lds[2] (R16-validated swizzle+read).
// B: reg-staged. Thread (c=tid&127, h=tid>>7) loads 16 coalesced f32 of
//    column n0+c, rows kg+16h..+15 (issued 1 ITER EARLY, 2 static reg slots);
//    packs 8 u32 (k even|odd bf16 pairs); 2 ds_write_b128 into Bu layout
//    u32 idx = c*16 + ((kp>>2)^((c>>2)&3))*4 + (kp&3)   [R7-validated].
// B-frag read: 1 ds_read_b128 per nf at byte c*64 + (ks^((c>>2)&3))*16 ->
//    bf16x8 in k-order directly (no cvt in MFMA path).
// Per iter: WRITE_Bu(it+1) [auto vmcnt(8): A(it) stays in flight];
//    LOAD_Bg(it+2); STAGE_A(it+1); vmcnt(24)+lgkmcnt(0)+s_barrier; compute.
// Bu 4-buffer (skew-safe), A_lds 2-buffer (R13/R16-measured safe).
// ---------------------------------------------------------------------------
template <typename OutT>
__global__ __launch_bounds__(256, 1) void gemm_pipe(
    const __bf16* __restrict__ A, const float* __restrict__ B,
    OutT* __restrict__ part, int N, int K, int kslice, int npad, int zshift) {
  __shared__ unsigned int Bu[4][2048];    // 4 x 8KB
  __shared__ __bf16 A_lds[2][512 * 32];   // 64 KB
  const int tid = threadIdx.x;
  const int lane = tid & 63;
  const int w = tid >> 6;  // 0..3
  const int bid = blockIdx.x;
  const int z = bid & ((1 << zshift) - 1);
  const int n0 = (bid >> zshift) * 128;
  const int kbeg = z * kslice;
  const int niters = kslice / BK;  // 98 or 16 -> even
  const int fr = lane & 15;
  const int ks = lane >> 4;

  f32x4 acc[8][8];
#pragma unroll
  for (int i = 0; i < 8; ++i)
#pragma unroll
    for (int j = 0; j < 8; ++j) acc[i][j] = (f32x4){0.f, 0.f, 0.f, 0.f};

  // A staging source (R2/R5/R16-validated swizzle)
  const int aswz = (lane & 3) ^ ((lane >> 2) & 3) ^ ((lane >> 4) & 3);
  const __bf16* Asrc =
      A + (size_t)(w * 128 + (lane >> 2)) * K + kbeg + aswz * 8;
  const int aslot = ks ^ ((fr & 3) ^ ((fr >> 2) & 3));

  // B staging: thread -> column c, k-half h (16 k-rows)
  const int bc = tid & 127;
  const int bh = tid >> 7;  // 0..1
  const float* Bgsrc = B + n0 + bc;
  const int bswz = (bc >> 2) & 3;
  // two 16B write slots: u32 idx = bc*16 + ((2h+j)^bswz)*4, j=0,1
  const int widx0 = bc * 16 + (((2 * bh) ^ bswz) << 2);
  const int widx1 = bc * 16 + (((2 * bh + 1) ^ bswz) << 2);

  bf16x8 af[8];  // constant-indexed only -> registers
  // B global 2-slot ping-pong (rule #20 static names)
  float gA0, gA1, gA2, gA3, gA4, gA5, gA6, gA7,
        gA8, gA9, gAa, gAb, gAc, gAd, gAe, gAf;
  float gB0, gB1, gB2, gB3, gB4, gB5, gB6, gB7,
        gB8, gB9, gBa, gBb, gBc, gBd, gBe, gBf;

#define STAGE_A(t)                                                        \
  {                                                                       \
    int off = (t) * BK;                                                   \
    if (off >= kslice) off = 0; /* dup tile; only read when t<niters */   \
    _Pragma("unroll") for (int i = 0; i < 8; ++i) {                       \
      gll16((const void*)(Asrc + (size_t)(i * 16) * K + off),             \
            (void*)&A_lds[(t) & 1][(w * 128 + i * 16) * 32]);             \
    }                                                                     \
  }

#define LOAD_BG(S, t)                                                     \
  {                                                                       \
    int off = (t) * BK;                                                   \
    if (off >= kslice) off = 0; /* dup tile, never consumed */            \
    const float* p = Bgsrc + (size_t)(kbeg + off + 16 * bh) * N;          \
    S##0 = p[0];            S##1 = p[(size_t)N];                          \
    S##2 = p[(size_t)2*N];  S##3 = p[(size_t)3*N];                        \
    S##4 = p[(size_t)4*N];  S##5 = p[(size_t)5*N];                        \
    S##6 = p[(size_t)6*N];  S##7 = p[(size_t)7*N];                        \
    S##8 = p[(size_t)8*N];  S##9 = p[(size_t)9*N];                        \
    S##a = p[(size_t)10*N]; S##b = p[(size_t)11*N];                       \
    S##c = p[(size_t)12*N]; S##d = p[(size_t)13*N];                       \
    S##e = p[(size_t)14*N]; S##f = p[(size_t)15*N];                       \
  }

#define PK(lo, hi)                                                        \
  ((unsigned int)(__bf16_raw{(__bf16)(lo)}.x) |                           \
   ((unsigned int)(__bf16_raw{(__bf16)(hi)}.x) << 16))

#define WRITE_BU(buf, S)                                                  \
  {                                                                       \
    union { __bf16 h[2]; unsigned int u; } q;                             \
    unsigned int u0, u1, u2, u3, u4, u5, u6, u7;                          \
    q.h[0] = (__bf16)S##0; q.h[1] = (__bf16)S##1; u0 = q.u;               \
    q.h[0] = (__bf16)S##2; q.h[1] = (__bf16)S##3; u1 = q.u;               \
    q.h[0] = (__bf16)S##4; q.h[1] = (__bf16)S##5; u2 = q.u;               \
    q.h[0] = (__bf16)S##6; q.h[1] = (__bf16)S##7; u3 = q.u;               \
    q.h[0] = (__bf16)S##8; q.h[1] = (__bf16)S##9; u4 = q.u;               \
    q.h[0] = (__bf16)S##a; q.h[1] = (__bf16)S##b; u5 = q.u;               \
    q.h[0] = (__bf16)S##c; q.h[1] = (__bf16)S##d; u6 = q.u;               \
    q.h[0] = (__bf16)S##e; q.h[1] = (__bf16)S##f; u7 = q.u;               \
    *(u32x4*)&Bu[buf][widx0] = (u32x4){u0, u1, u2, u3};                   \
    *(u32x4*)&Bu[buf][widx1] = (u32x4){u4, u5, u6, u7};                   \
  }

  // prologue: Bg(0)->gA, Bg(1)->gB, A(0); write Bu[0] from gA
  LOAD_BG(gA, 0);
  LOAD_BG(gB, 1);
  STAGE_A(0);
  WRITE_BU(0, gA);

  // iter it: WRITE_Bu[(it+1)&3] from slot (it+1)&1 (loaded iter it-1;
  // compiler auto-waits counted vmcnt, A(it) stays in flight);
  // LOAD_Bg(it+2) -> slot it&1; STAGE_A(it+1); vmcnt(24) drains A(it).
#define BODY(it, WRS, LDS_)                                               \
  {                                                                       \
    if ((it) + 1 < niters) WRITE_BU(((it) + 1) & 3, WRS);                 \
    LOAD_BG(LDS_, (it) + 2);                                              \
    STAGE_A((it) + 1);                                                    \
    asm volatile("s_waitcnt vmcnt(24)" ::: "memory");                     \
    asm volatile("s_waitcnt lgkmcnt(0)" ::: "memory");                    \
    __builtin_amdgcn_s_barrier();                                         \
    __builtin_amdgcn_sched_barrier(0);                                    \
    {                                                                     \
      const __bf16* al = &A_lds[(it) & 1][0];                             \
      _Pragma("unroll") for (int mf = 0; mf < 8; ++mf)                    \
          af[mf] = *(const bf16x8*)(al + (w * 128 + mf * 16 + fr) * 32 +  \
                                    aslot * 8);                           \
    }                                                                     \
    const unsigned int* bl = &Bu[(it) & 3][0];                            \
    bf16x8 bf0, bf1;                                                      \
    bf0 = *(const bf16x8*)((const char*)bl +                              \
                           (0 * 16 + fr) * 64 + (ks ^ ((fr >> 2) & 3)) * 16); \
    _Pragma("unroll") for (int nf = 0; nf < 8; ++nf) {                    \
      const int c_ = nf * 16 + fr;                                        \
      if (nf + 1 < 8) {                                                   \
        const int cn_ = (nf + 1) * 16 + fr;                               \
        bf1 = *(const bf16x8*)((const char*)bl + cn_ * 64 +               \
                               (ks ^ ((cn_ >> 2) & 3)) * 16);             \
      }                                                                   \
      (void)c_;                                                           \
      _Pragma("unroll") for (int mf = 0; mf < 8; ++mf)                    \
          acc[mf][nf] = __builtin_amdgcn_mfma_f32_16x16x32_bf16(          \
              af[mf], bf0, acc[mf][nf], 0, 0, 0);                         \
      bf0 = bf1;                                                          \
    }                                                                     \
  }

  for (int it = 0; it < niters; it += 2) {
    BODY(it, gB, gA);       // write Bu(it+1) from gB, load Bg(it+2)->gA
    BODY(it + 1, gA, gB);   // write Bu(it+2) from gA, load Bg(it+3)->gB
  }
#undef BODY
#undef WRITE_BU
#undef LOAD_BG
#undef STAGE_A

  // epilogue: C/D layout col = lane&15, row = (lane>>4)*4 + r
  const int r0 = ks * 4;
  OutT* pbase = part + (size_t)z * 512 * npad;
#pragma unroll
  for (int mf = 0; mf < 8; ++mf)
#pragma unroll
    for (int nf = 0; nf < 8; ++nf) {
      const int col = n0 + nf * 16 + fr;
#pragma unroll
      for (int r = 0; r < 4; ++r) {
        const int row = w * 128 + mf * 16 + r0 + r;
        pbase[(size_t)row * npad + col] = (OutT)acc[mf][nf][r];
      }
    }
}

// ---------------------------------------------------------------------------
// gemm_small (R12-validated): barrier-free LDS-free, per-wave 128x64 tile.
// ---------------------------------------------------------------------------
template <typename OutT>
__global__ __launch_bounds__(256, 1) void gemm_small(
    const __bf16* __restrict__ A, const float* __restrict__ B,
    OutT* __restrict__ part, int N, int K, int kslice, int npad, int zshift) {
  const int tid = threadIdx.x;
  const int lane = tid & 63;
  const int w = tid >> 6;
  const int bid = blockIdx.x;
  const int z = bid & ((1 << zshift) - 1);
  const int n0 = (bid >> zshift) * 64;
  const int kbeg = z * kslice;
  const int niters = kslice / BK;
  const int kmax = kbeg + kslice;
  const int fr = lane & 15;
  const int ks = lane >> 4;
  const int m0 = w * 128;
  const bool fullN = (n0 + 64) <= N;

  f32x4 acc[8][4];
#pragma unroll
  for (int i = 0; i < 8; ++i)
#pragma unroll
    for (int j = 0; j < 4; ++j) acc[i][j] = (f32x4){0.f, 0.f, 0.f, 0.f};

  const __bf16* Abase = A + (size_t)(m0 + fr) * K + ks * 8;
  const size_t Astride = (size_t)16 * K;
  const float* Bbase = B + n0 + fr;

  bf16x8 afA[8], afB[8];
  float bA[32], bB[32];

#define LOAD_A(D, t)                                                     \
  {                                                                      \
    int kk = kbeg + (t) * BK;                                            \
    if (kk >= kmax) kk = kbeg;                                           \
    const __bf16* ap = Abase + kk;                                       \
    _Pragma("unroll") for (int i = 0; i < 8; ++i)                        \
        D[i] = *(const bf16x8*)(ap + (size_t)i * Astride);               \
  }

#define LOAD_B(S, t)                                                     \
  {                                                                      \
    int kg = kbeg + (t) * BK;                                            \
    if (kg >= kmax) kg = kbeg;                                           \
    const float* p = Bbase + (size_t)(kg + ks * 8) * N;                  \
    if (fullN) {                                                         \
      _Pragma("unroll") for (int e = 0; e < 8; ++e) {                    \
        _Pragma("unroll") for (int nf = 0; nf < 4; ++nf)                 \
            S[e * 4 + nf] = p[nf * 16];                                  \
        p += N;                                                          \
      }                                                                  \
    } else {                                                             \
      _Pragma("unroll") for (int e = 0; e < 8; ++e) {                    \
        _Pragma("unroll") for (int nf = 0; nf < 4; ++nf)                 \
            S[e * 4 + nf] =                                              \
                (n0 + nf * 16 + fr < N) ? p[nf * 16] : 0.f;              \
        p += N;                                                          \
      }                                                                  \
    }                                                                    \
  }

#define BODY(it, CA, NA, CB)                                             \
  {                                                                      \
    bf16x8 bfr[4];                                                       \
    _Pragma("unroll") for (int e = 0; e < 8; ++e)                        \
        _Pragma("unroll") for (int nf = 0; nf < 4; ++nf)                 \
            bfr[nf][e] = (__bf16)CB[e * 4 + nf];                         \
    LOAD_B(CB, (it) + 2);                                                \
    LOAD_A(NA, (it) + 1);                                                \
    _Pragma("unroll") for (int nf = 0; nf < 4; ++nf)                     \
        _Pragma("unroll") for (int mf = 0; mf < 8; ++mf)                 \
            acc[mf][nf] = __builtin_amdgcn_mfma_f32_16x16x32_bf16(       \
                CA[mf], bfr[nf], acc[mf][nf], 0, 0, 0);                  \
  }

  LOAD_A(afA, 0);
  LOAD_B(bA, 0);
  LOAD_B(bB, 1);
  for (int it = 0; it < niters; it += 2) {
    BODY(it, afA, afB, bA);
    BODY(it + 1, afB, afA, bB);
  }
#undef BODY
#undef LOAD_B
#undef LOAD_A

  const int r0 = ks * 4;
  OutT* pbase = part + (size_t)z * 512 * npad;
#pragma unroll
  for (int mf = 0; mf < 8; ++mf)
#pragma unroll
    for (int nf = 0; nf < 4; ++nf) {
      const int col = n0 + nf * 16 + fr;
#pragma unroll
      for (int r = 0; r < 4; ++r) {
        const int row = m0 + mf * 16 + r0 + r;
        pbase[(size_t)row * npad + col] = (OutT)acc[mf][nf][r];
      }
    }
}

// sum bf16 split-K partials + bias, relu -> bf16 activations [512][4096]
__global__ __launch_bounds__(256) void reduce_relu_kernel(
    const __bf16* __restrict__ part, const float* __restrict__ bias,
    __bf16* __restrict__ out, int nsplit) {
  const int idx = blockIdx.x * 256 + threadIdx.x;
  const int flat = idx * 8;
  if (flat >= 512 * 4096) return;
  float s[8];
#pragma unroll
  for (int j = 0; j < 8; ++j) s[j] = 0.f;
  for (int sp = 0; sp < nsplit; ++sp) {
    bf16x8 v = *(const bf16x8*)(part + (size_t)sp * (512 * 4096) + flat);
#pragma unroll
    for (int j = 0; j < 8; ++j) s[j] += (float)v[j];
  }
  const int nb = flat & 4095;
  bf16x8 o;
#pragma unroll
  for (int j = 0; j < 8; ++j) {
    float v = s[j] + bias[nb + j];
    o[j] = (__bf16)(v > 0.f ? v : 0.f);
  }
  *(bf16x8*)(out + flat) = o;
}

// final: sum split-K fp32 partials (stride 128) + bias -> d_out fp32
__global__ __launch_bounds__(256) void reduce_out_kernel(
    const float* __restrict__ pc, const float* __restrict__ pr,
    const float* __restrict__ bcls, const float* __restrict__ breg,
    float* __restrict__ out, int nsplit) {
  const int gid = blockIdx.x * 256 + threadIdx.x;
  if (gid >= 512 * 105) return;
  if (gid < 512 * 21) {
    const int m = gid / 21, j = gid - m * 21;
    float s = bcls[j];
    for (int sp = 0; sp < nsplit; ++sp)
      s += pc[(size_t)sp * 512 * 128 + m * 128 + j];
    out[gid] = s;
  } else {
    const int g = gid - 512 * 21;
    const int m = g / 84, j = g - m * 84;
    float s = breg[j];
    for (int sp = 0; sp < nsplit; ++sp)
      s += pr[(size_t)sp * 512 * 128 + m * 128 + j];
    out[gid] = s;
  }
}

extern "C" void kernel_launch(void* const* d_in, const int* in_sizes, int n_in,
                              void* d_out, int out_size, void* d_ws, size_t ws_size,
                              hipStream_t stream) {
  (void)in_sizes; (void)n_in; (void)out_size;
  const float* x    = (const float*)d_in[0];
  const float* rois = (const float*)d_in[2];
  const float* W1   = (const float*)d_in[3];
  const float* b1   = (const float*)d_in[4];
  const float* W2   = (const float*)d_in[5];
  const float* b2   = (const float*)d_in[6];
  const float* Wcls = (const float*)d_in[7];
  const float* bcls = (const float*)d_in[8];
  const float* Wreg = (const float*)d_in[9];
  const float* breg = (const float*)d_in[10];
  float* out = (float*)d_out;

  const size_t pooled_b = (size_t)512 * KK1 * 2;        // 25,690,112
  const size_t act_b = (size_t)512 * D1 * 2;            // 4 MiB
  const size_t need8 = pooled_b + (size_t)8 * act_b + 2 * act_b;
  const int ns = (ws_size >= need8) ? 8 : 2;            // ws ~1.6GB: ns=8
  const int zshift = (ns == 8) ? 3 : 1;

  char* ws = (char*)d_ws;
  __bf16* pooled = (__bf16*)ws;
  __bf16* part1 = (__bf16*)(ws + pooled_b);             // ns * 4MiB
  __bf16* f1 = (__bf16*)(ws + pooled_b + (size_t)ns * act_b);
  __bf16* f2 = (__bf16*)(ws + pooled_b + (size_t)ns * act_b + act_b);
  __bf16* part2 = (__bf16*)ws;                          // alias dead pooled+part1
  float* pcls = (float*)ws;                             // heads phase aliases
  float* preg = (float*)(ws + (size_t)64 * 512 * 128 * 4);  // +16.8MB

  // 1) RoIPool -> pooled bf16 [512, 25088]
  roipool_kernel<<<N_ROIS * 8, 256, 0, stream>>>(x, rois, pooled);

  // 2) GEMM1: pooled @ W1[25088,4096]; W1 read exactly once; z-pinned XCDs
  gemm_pipe<__bf16><<<32 * ns, 256, 0, stream>>>(
      pooled, W1, part1, 4096, KK1, KK1 / ns, 4096, zshift);
  reduce_relu_kernel<<<1024, 256, 0, stream>>>(part1, b1, f1, ns);

  // 3) GEMM2: f1 @ W2[4096,4096]
  gemm_pipe<__bf16><<<32 * ns, 256, 0, stream>>>(
      f1, W2, part2, 4096, 4096, 4096 / ns, 4096, zshift);
  reduce_relu_kernel<<<1024, 256, 0, stream>>>(part2, b2, f2, ns);

  // 4) heads via gemm_small (N<128-safe), split-K=64
  gemm_small<float><<<64, 256, 0, stream>>>(
      f2, Wcls, pcls, 21, 4096, 64, 128, 6);
  gemm_small<float><<<128, 256, 0, stream>>>(
      f2, Wreg, preg, 84, 4096, 64, 128, 6);
  reduce_out_kernel<<<(512 * 105 + 255) / 256, 256, 0, stream>>>(
      pcls, preg, bcls, breg, out, 64);
}

// Round 18
// 371.288 us; speedup vs baseline: 1.0834x; 1.0834x over previous
//
#include <hip/hip_runtime.h>

// ---------------------------------------------------------------------------
// FastRCNN head: RoIPool + FC(25088->4096) + FC(4096->4096) + heads (21/84).
// R18: m97-shaped GEMM — the missing lever across R11-R17 was TLP (every good
// inner loop ran 1 block/CU, occupancy 11%; R2 at 41% occ beat them with a
// worse loop). BM=BN=128, 4 waves of 64x64 (acc[4][4]=64 AGPR), (256,3) ->
// ~136 regs -> 3 blocks/CU = 12 waves/CU (m114 overlap hides the barrier
// drain). B reg-staged -> pair-packed bf16 Bu (R7/R17-validated layout,
// 1 ds_read_b128 per nf, cvt off the MFMA path); A via gll16 (R16 swizzle).
// One __syncthreads per iter (m97 pattern). Grid: z innermost (XCD pin),
// mt next (4 m-tiles share W1 panels in L2/L3), nt outer.
// ---------------------------------------------------------------------------

typedef __attribute__((ext_vector_type(8))) __bf16 bf16x8;
typedef __attribute__((ext_vector_type(4))) float f32x4;
typedef __attribute__((ext_vector_type(4))) unsigned int u32x4;

#define N_ROIS 512
#define FH 50
#define FW 50
#define KK1 25088      // 512*49
#define D1 4096
#define BK 32

__device__ __forceinline__ void gll16(const void* g, void* l) {
  __builtin_amdgcn_global_load_lds(
      (const __attribute__((address_space(1))) void*)g,
      (__attribute__((address_space(3))) void*)l, 16, 0, 0);
}

// ---------------------------------------------------------------------------
// RoIPool: block = (roi, channel-group of 64). 4096 blocks (validated R5-R17).
// ---------------------------------------------------------------------------
__global__ __launch_bounds__(256) void roipool_kernel(
    const float* __restrict__ x, const float* __restrict__ rois,
    __bf16* __restrict__ pooled) {
  const int bid = blockIdx.x;
  const int roi = bid >> 3;
  const int cg = bid & 7;
  const float s = 0.0625f;
  const float r0 = rois[roi * 4 + 0], r1 = rois[roi * 4 + 1];
  const float r2 = rois[roi * 4 + 2], r3 = rois[roi * 4 + 3];
  int x1 = (int)(r0 * s); x1 = min(max(x1, 0), FW - 1);
  int y1 = (int)(r1 * s); y1 = min(max(y1, 0), FH - 1);
  int x2 = (int)(r2 * s); x2 = min(max(x2, 0), FW - 1);
  int y2 = (int)(r3 * s); y2 = min(max(y2, 0), FH - 1);
  const int ww = x2 - x1 + 1, hh = y2 - y1 + 1;
  __shared__ int cs[7], ce[7], rs[7], re[7];
  if (threadIdx.x < 7) {
    int i = threadIdx.x;
    cs[i] = x1 + (i * ww) / 7;
    ce[i] = x1 + ((i + 1) * ww + 6) / 7;
    rs[i] = y1 + (i * hh) / 7;
    re[i] = y1 + ((i + 1) * hh + 6) / 7;
  }
  __syncthreads();
  for (int idx = threadIdx.x; idx < 64 * 49; idx += 256) {
    int cl = idx / 49;
    int p = idx - cl * 49;
    int py = p / 7, px = p - py * 7;
    const int c = cg * 64 + cl;
    const float* base = x + (size_t)c * (FH * FW);
    float m = -3.402823466e38f;
    for (int y = rs[py]; y < re[py]; ++y) {
      const float* rowp = base + y * FW;
      for (int xx = cs[px]; xx < ce[px]; ++xx) m = fmaxf(m, rowp[xx]);
    }
    pooled[(size_t)roi * KK1 + c * 49 + p] = (__bf16)m;
  }
}

// ---------------------------------------------------------------------------
// gemm_pipe: part[z][512][npad] = A[512,K](bf16) @ B[K,N](fp32, N%128==0)
// Block tile 128x128; 256 thr = 4 waves (wm=w>>1, wn=w&1), wave 64x64.
// bid: z = bid & (ns-1); rest = bid>>zshift; mt = rest&3; nt = rest>>2.
// A: 2 gll16/wave/iter -> A_lds[2][128*32] bf16 (R16-validated swizzle).
// B: thread (c=tid&127, h=tid>>7) loads 16 coalesced f32 of col nt*128+c,
//    rows kg+16h..+15; packs k-pairs; 2 ds_write_b128 into Bu
//    (u32 idx = c*16 + ((kp>>2)^((c>>2)&3))*4 + (kp&3), R7/R17-validated).
// B-frag: 1 ds_read_b128 per nf at byte c*64 + (ks^((c>>2)&3))*16.
// Sync: single __syncthreads per iter (m97); TLP (3 blocks/CU) hides drain.
// ---------------------------------------------------------------------------
template <typename OutT>
__global__ __launch_bounds__(256, 3) void gemm_pipe(
    const __bf16* __restrict__ A, const float* __restrict__ B,
    OutT* __restrict__ part, int N, int K, int kslice, int npad, int zshift) {
  __shared__ unsigned int Bu[2][2048];    // 2 x 8KB (bf16 pairs)
  __shared__ __bf16 A_lds[2][128 * 32];   // 2 x 8KB
  const int tid = threadIdx.x;
  const int lane = tid & 63;
  const int w = tid >> 6;  // 0..3
  const int wm = w >> 1, wn = w & 1;
  const int bid = blockIdx.x;
  const int z = bid & ((1 << zshift) - 1);
  const int rest = bid >> zshift;
  const int mt = rest & 3;
  const int nt = rest >> 2;
  const int n0 = nt * 128;
  const int m0 = mt * 128;
  const int kbeg = z * kslice;
  const int niters = kslice / BK;  // 98 or 16
  const int fr = lane & 15;
  const int ks = lane >> 4;

  f32x4 acc[4][4];
#pragma unroll
  for (int i = 0; i < 4; ++i)
#pragma unroll
    for (int j = 0; j < 4; ++j) acc[i][j] = (f32x4){0.f, 0.f, 0.f, 0.f};

  // A staging (R2/R5/R16-validated swizzle): wave w stages rows
  // w*32 + i*16 + (lane>>2), i=0..1; source col offset aswz*8.
  const int aswz = (lane & 3) ^ ((lane >> 2) & 3) ^ ((lane >> 4) & 3);
  const __bf16* Asrc =
      A + (size_t)(m0 + w * 32 + (lane >> 2)) * K + kbeg + aswz * 8;
  const int aslot = ks ^ ((fr & 3) ^ ((fr >> 2) & 3));

  // B staging: thread -> column c, k-half h (16 rows)
  const int bc = tid & 127;
  const int bh = tid >> 7;  // 0..1
  const float* Bgsrc = B + n0 + bc;
  const int bswz = (bc >> 2) & 3;
  const int widx0 = bc * 16 + (((2 * bh) ^ bswz) << 2);
  const int widx1 = bc * 16 + (((2 * bh + 1) ^ bswz) << 2);

  // B global regs: single slot (loaded iter it for tile it+1, written same
  // iter after compute — slack = compute phase; TLP hides the rest)
  float g0, g1, g2, g3, g4, g5, g6, g7, g8, g9, ga, gb, gc, gd, ge, gf;

#define LOAD_BG(t)                                                        \
  {                                                                       \
    int off = (t) * BK;                                                   \
    if (off >= kslice) off = 0; /* dup tile, never consumed */            \
    const float* p = Bgsrc + (size_t)(kbeg + off + 16 * bh) * N;          \
    g0 = p[0];            g1 = p[(size_t)N];                              \
    g2 = p[(size_t)2*N];  g3 = p[(size_t)3*N];                            \
    g4 = p[(size_t)4*N];  g5 = p[(size_t)5*N];                            \
    g6 = p[(size_t)6*N];  g7 = p[(size_t)7*N];                            \
    g8 = p[(size_t)8*N];  g9 = p[(size_t)9*N];                            \
    ga = p[(size_t)10*N]; gb = p[(size_t)11*N];                           \
    gc = p[(size_t)12*N]; gd = p[(size_t)13*N];                           \
    ge = p[(size_t)14*N]; gf = p[(size_t)15*N];                           \
  }

#define WRITE_BU(buf)                                                     \
  {                                                                       \
    union { __bf16 h[2]; unsigned int u; } q;                             \
    unsigned int u0, u1, u2, u3, u4, u5, u6, u7;                          \
    q.h[0] = (__bf16)g0; q.h[1] = (__bf16)g1; u0 = q.u;                   \
    q.h[0] = (__bf16)g2; q.h[1] = (__bf16)g3; u1 = q.u;                   \
    q.h[0] = (__bf16)g4; q.h[1] = (__bf16)g5; u2 = q.u;                   \
    q.h[0] = (__bf16)g6; q.h[1] = (__bf16)g7; u3 = q.u;                   \
    q.h[0] = (__bf16)g8; q.h[1] = (__bf16)g9; u4 = q.u;                   \
    q.h[0] = (__bf16)ga; q.h[1] = (__bf16)gb; u5 = q.u;                   \
    q.h[0] = (__bf16)gc; q.h[1] = (__bf16)gd; u6 = q.u;                   \
    q.h[0] = (__bf16)ge; q.h[1] = (__bf16)gf; u7 = q.u;                   \
    *(u32x4*)&Bu[buf][widx0] = (u32x4){u0, u1, u2, u3};                   \
    *(u32x4*)&Bu[buf][widx1] = (u32x4){u4, u5, u6, u7};                   \
  }

#define STAGE_A(t)                                                        \
  {                                                                       \
    int off = (t) * BK;                                                   \
    if (off >= kslice) off = 0; /* dup tile; only read when t<niters */   \
    _Pragma("unroll") for (int i = 0; i < 2; ++i) {                       \
      gll16((const void*)(Asrc + (size_t)(i * 16) * K + off),             \
            (void*)&A_lds[(t) & 1][(w * 32 + i * 16) * 32]);              \
    }                                                                     \
  }

  // prologue: tile 0 into buffers
  LOAD_BG(0);
  STAGE_A(0);
  WRITE_BU(0);
  __syncthreads();

  for (int it = 0; it < niters; ++it) {
    const int cur = it & 1;
    const bool more = (it + 1) < niters;
    if (more) {
      LOAD_BG(it + 1);      // global->reg, retired by WRITE_BU below
      STAGE_A(it + 1);      // gll16 -> A_lds[cur^1]
    }
    // compute on A_lds[cur], Bu[cur]
    bf16x8 af[4];
    {
      const __bf16* al = &A_lds[cur][0];
#pragma unroll
      for (int mf = 0; mf < 4; ++mf)
        af[mf] = *(const bf16x8*)(al + (wm * 64 + mf * 16 + fr) * 32 +
                                  aslot * 8);
    }
    const unsigned int* bl = &Bu[cur][0];
#pragma unroll
    for (int nf = 0; nf < 4; ++nf) {
      const int c = wn * 64 + nf * 16 + fr;
      bf16x8 bfr = *(const bf16x8*)((const char*)bl + c * 64 +
                                    (ks ^ ((c >> 2) & 3)) * 16);
#pragma unroll
      for (int mf = 0; mf < 4; ++mf)
        acc[mf][nf] = __builtin_amdgcn_mfma_f32_16x16x32_bf16(
            af[mf], bfr, acc[mf][nf], 0, 0, 0);
    }
    if (more) WRITE_BU(cur ^ 1);  // cvt+pack+2 ds_write (waits its vmcnt)
    __syncthreads();
  }
#undef STAGE_A
#undef WRITE_BU
#undef LOAD_BG

  // epilogue: C/D layout col = lane&15, row = (lane>>4)*4 + r
  const int r0 = ks * 4;
  OutT* pbase = part + (size_t)z * 512 * npad;
#pragma unroll
  for (int mf = 0; mf < 4; ++mf)
#pragma unroll
    for (int nf = 0; nf < 4; ++nf) {
      const int col = n0 + wn * 64 + nf * 16 + fr;
#pragma unroll
      for (int r = 0; r < 4; ++r) {
        const int row = m0 + wm * 64 + mf * 16 + r0 + r;
        pbase[(size_t)row * npad + col] = (OutT)acc[mf][nf][r];
      }
    }
}

// ---------------------------------------------------------------------------
// gemm_small (R12-validated): barrier-free LDS-free, per-wave 128x64 tile.
// Used for the tiny head GEMMs (handles N < 64 via per-lane guards).
// ---------------------------------------------------------------------------
template <typename OutT>
__global__ __launch_bounds__(256, 1) void gemm_small(
    const __bf16* __restrict__ A, const float* __restrict__ B,
    OutT* __restrict__ part, int N, int K, int kslice, int npad, int zshift) {
  const int tid = threadIdx.x;
  const int lane = tid & 63;
  const int w = tid >> 6;
  const int bid = blockIdx.x;
  const int z = bid & ((1 << zshift) - 1);
  const int n0 = (bid >> zshift) * 64;
  const int kbeg = z * kslice;
  const int niters = kslice / BK;
  const int kmax = kbeg + kslice;
  const int fr = lane & 15;
  const int ks = lane >> 4;
  const int m0 = w * 128;
  const bool fullN = (n0 + 64) <= N;

  f32x4 acc[8][4];
#pragma unroll
  for (int i = 0; i < 8; ++i)
#pragma unroll
    for (int j = 0; j < 4; ++j) acc[i][j] = (f32x4){0.f, 0.f, 0.f, 0.f};

  const __bf16* Abase = A + (size_t)(m0 + fr) * K + ks * 8;
  const size_t Astride = (size_t)16 * K;
  const float* Bbase = B + n0 + fr;

  bf16x8 afA[8], afB[8];
  float bA[32], bB[32];

#define LOAD_A(D, t)                                                     \
  {                                                                      \
    int kk = kbeg + (t) * BK;                                            \
    if (kk >= kmax) kk = kbeg;                                           \
    const __bf16* ap = Abase + kk;                                       \
    _Pragma("unroll") for (int i = 0; i < 8; ++i)                        \
        D[i] = *(const bf16x8*)(ap + (size_t)i * Astride);               \
  }

#define LOAD_B(S, t)                                                     \
  {                                                                      \
    int kg = kbeg + (t) * BK;                                            \
    if (kg >= kmax) kg = kbeg;                                           \
    const float* p = Bbase + (size_t)(kg + ks * 8) * N;                  \
    if (fullN) {                                                         \
      _Pragma("unroll") for (int e = 0; e < 8; ++e) {                    \
        _Pragma("unroll") for (int nf = 0; nf < 4; ++nf)                 \
            S[e * 4 + nf] = p[nf * 16];                                  \
        p += N;                                                          \
      }                                                                  \
    } else {                                                             \
      _Pragma("unroll") for (int e = 0; e < 8; ++e) {                    \
        _Pragma("unroll") for (int nf = 0; nf < 4; ++nf)                 \
            S[e * 4 + nf] =                                              \
                (n0 + nf * 16 + fr < N) ? p[nf * 16] : 0.f;              \
        p += N;                                                          \
      }                                                                  \
    }                                                                    \
  }

#define BODY(it, CA, NA, CB)                                             \
  {                                                                      \
    bf16x8 bfr[4];                                                       \
    _Pragma("unroll") for (int e = 0; e < 8; ++e)                        \
        _Pragma("unroll") for (int nf = 0; nf < 4; ++nf)                 \
            bfr[nf][e] = (__bf16)CB[e * 4 + nf];                         \
    LOAD_B(CB, (it) + 2);                                                \
    LOAD_A(NA, (it) + 1);                                                \
    _Pragma("unroll") for (int nf = 0; nf < 4; ++nf)                     \
        _Pragma("unroll") for (int mf = 0; mf < 8; ++mf)                 \
            acc[mf][nf] = __builtin_amdgcn_mfma_f32_16x16x32_bf16(       \
                CA[mf], bfr[nf], acc[mf][nf], 0, 0, 0);                  \
  }

  LOAD_A(afA, 0);
  LOAD_B(bA, 0);
  LOAD_B(bB, 1);
  for (int it = 0; it < niters; it += 2) {
    BODY(it, afA, afB, bA);
    BODY(it + 1, afB, afA, bB);
  }
#undef BODY
#undef LOAD_B
#undef LOAD_A

  const int r0 = ks * 4;
  OutT* pbase = part + (size_t)z * 512 * npad;
#pragma unroll
  for (int mf = 0; mf < 8; ++mf)
#pragma unroll
    for (int nf = 0; nf < 4; ++nf) {
      const int col = n0 + nf * 16 + fr;
#pragma unroll
      for (int r = 0; r < 4; ++r) {
        const int row = m0 + mf * 16 + r0 + r;
        pbase[(size_t)row * npad + col] = (OutT)acc[mf][nf][r];
      }
    }
}

// sum bf16 split-K partials + bias, relu -> bf16 activations [512][4096]
__global__ __launch_bounds__(256) void reduce_relu_kernel(
    const __bf16* __restrict__ part, const float* __restrict__ bias,
    __bf16* __restrict__ out, int nsplit) {
  const int idx = blockIdx.x * 256 + threadIdx.x;
  const int flat = idx * 8;
  if (flat >= 512 * 4096) return;
  float s[8];
#pragma unroll
  for (int j = 0; j < 8; ++j) s[j] = 0.f;
  for (int sp = 0; sp < nsplit; ++sp) {
    bf16x8 v = *(const bf16x8*)(part + (size_t)sp * (512 * 4096) + flat);
#pragma unroll
    for (int j = 0; j < 8; ++j) s[j] += (float)v[j];
  }
  const int nb = flat & 4095;
  bf16x8 o;
#pragma unroll
  for (int j = 0; j < 8; ++j) {
    float v = s[j] + bias[nb + j];
    o[j] = (__bf16)(v > 0.f ? v : 0.f);
  }
  *(bf16x8*)(out + flat) = o;
}

// final: sum split-K fp32 partials (stride 128) + bias -> d_out fp32
__global__ __launch_bounds__(256) void reduce_out_kernel(
    const float* __restrict__ pc, const float* __restrict__ pr,
    const float* __restrict__ bcls, const float* __restrict__ breg,
    float* __restrict__ out, int nsplit) {
  const int gid = blockIdx.x * 256 + threadIdx.x;
  if (gid >= 512 * 105) return;
  if (gid < 512 * 21) {
    const int m = gid / 21, j = gid - m * 21;
    float s = bcls[j];
    for (int sp = 0; sp < nsplit; ++sp)
      s += pc[(size_t)sp * 512 * 128 + m * 128 + j];
    out[gid] = s;
  } else {
    const int g = gid - 512 * 21;
    const int m = g / 84, j = g - m * 84;
    float s = breg[j];
    for (int sp = 0; sp < nsplit; ++sp)
      s += pr[(size_t)sp * 512 * 128 + m * 128 + j];
    out[gid] = s;
  }
}

extern "C" void kernel_launch(void* const* d_in, const int* in_sizes, int n_in,
                              void* d_out, int out_size, void* d_ws, size_t ws_size,
                              hipStream_t stream) {
  (void)in_sizes; (void)n_in; (void)out_size;
  const float* x    = (const float*)d_in[0];
  const float* rois = (const float*)d_in[2];
  const float* W1   = (const float*)d_in[3];
  const float* b1   = (const float*)d_in[4];
  const float* W2   = (const float*)d_in[5];
  const float* b2   = (const float*)d_in[6];
  const float* Wcls = (const float*)d_in[7];
  const float* bcls = (const float*)d_in[8];
  const float* Wreg = (const float*)d_in[9];
  const float* breg = (const float*)d_in[10];
  float* out = (float*)d_out;

  const size_t pooled_b = (size_t)512 * KK1 * 2;        // 25,690,112
  const size_t act_b = (size_t)512 * D1 * 2;            // 4 MiB
  const size_t need8 = pooled_b + (size_t)8 * act_b + 2 * act_b;
  const int ns = (ws_size >= need8) ? 8 : 2;            // ws ~1.6GB: ns=8
  const int zshift = (ns == 8) ? 3 : 1;

  char* ws = (char*)d_ws;
  __bf16* pooled = (__bf16*)ws;
  __bf16* part1 = (__bf16*)(ws + pooled_b);             // ns * 4MiB
  __bf16* f1 = (__bf16*)(ws + pooled_b + (size_t)ns * act_b);
  __bf16* f2 = (__bf16*)(ws + pooled_b + (size_t)ns * act_b + act_b);
  __bf16* part2 = (__bf16*)ws;                          // alias dead pooled+part1
  float* pcls = (float*)ws;                             // heads phase aliases
  float* preg = (float*)(ws + (size_t)64 * 512 * 128 * 4);  // +16.8MB

  // 1) RoIPool -> pooled bf16 [512, 25088]
  roipool_kernel<<<N_ROIS * 8, 256, 0, stream>>>(x, rois, pooled);

  // 2) GEMM1: pooled @ W1[25088,4096]; grid = nt(32) x mt(4) x z(ns)
  gemm_pipe<__bf16><<<32 * 4 * ns, 256, 0, stream>>>(
      pooled, W1, part1, 4096, KK1, KK1 / ns, 4096, zshift);
  reduce_relu_kernel<<<1024, 256, 0, stream>>>(part1, b1, f1, ns);

  // 3) GEMM2: f1 @ W2[4096,4096]
  gemm_pipe<__bf16><<<32 * 4 * ns, 256, 0, stream>>>(
      f1, W2, part2, 4096, 4096, 4096 / ns, 4096, zshift);
  reduce_relu_kernel<<<1024, 256, 0, stream>>>(part2, b2, f2, ns);

  // 4) heads via gemm_small (N<128-safe), split-K=64
  gemm_small<float><<<64, 256, 0, stream>>>(
      f2, Wcls, pcls, 21, 4096, 64, 128, 6);
  gemm_small<float><<<128, 256, 0, stream>>>(
      f2, Wreg, preg, 84, 4096, 64, 128, 6);
  reduce_out_kernel<<<(512 * 105 + 255) / 256, 256, 0, stream>>>(
      pcls, preg, bcls, breg, out, 64);
}